// Round 11
// baseline (150.727 us; speedup 1.0000x reference)
//
#include <hip/hip_runtime.h>
#include <cfloat>
#include <climits>

#define ROWS    1024
#define VOCABSZ 128000
#define NBEAMS  16
#define NBATCH  64
#define CURLEN  8
#define KTOP    16
#define WPB     4                    // waves per block (kernel 1)
#define SPLIT   2                    // blocks per row (asymmetric 63/62 steps)
#define BASE1   64512                // block1 element base (63*1024)
#define TCAP    96                   // tuple slots per wave (float4 + base)
#define TGUARD  80                   // stop appending past this (ovf -> rescue)
#define RCAP    (4 * TCAP)           // rescue/expand per-element capacity (384)
#define RFLUSH  320                  // rescue mid-flush threshold
#define LOG2E   1.4426950408889634f
#define LN2     0.6931471805599453f
#define THRY    (3.10f * LOG2E)      // static threshold, y-domain (~62/block expected)

#if __has_builtin(__builtin_amdgcn_exp2f)
#define EXP2(x) __builtin_amdgcn_exp2f(x)
#else
#define EXP2(x) exp2f(x)
#endif

// ---------------------------------------------------------------------------
// Kernel 1: 2 blocks per row (63/62 float4-steps). Tiny rolled hot loop
// (#pragma unroll 1, depth-4 prefetch): per step 4 mul + 4 exp2 + 4 add +
// 3 max + 1 cmp + wave-uniform branch. Passing lanes (~11% of steps) store
// one float4 tuple + base via single ballot. ALL top-k machinery is cold
// code after the loop. __launch_bounds__(256,8) pins VGPR<=64 so 8 blocks/CU
// (32 waves/CU) are resident; LDS ~14 KB.
// Correctness for ANY input: wave ovf or block above-count<16 -> exact
// per-wave rescan+flush (cold; prob ~0 for N(0,1) data).
// ---------------------------------------------------------------------------
__global__ __launch_bounds__(256, 8) void k1_scan(const float* __restrict__ logits,
                                                  float* __restrict__ wsS,
                                                  float* __restrict__ wsV,
                                                  int* __restrict__ wsI) {
    __shared__ float4 tup[WPB][TCAP];      // 6 KB   (aliased by rescue values)
    __shared__ int    tub[WPB][TCAP];      // 1.5 KB
    __shared__ int    rbix[WPB][RCAP];     // 6 KB   rescue indices
    __shared__ float  redS[WPB];
    __shared__ int    redC[WPB];

    const int gb    = blockIdx.x;
    const int row   = gb >> 1;
    const int blk   = gb & 1;
    const int ebase = blk ? BASE1 : 0;        // element base within row
    const int nstep = blk ? 62 : 63;          // float4-steps in this block
    const int t     = threadIdx.x;
    const int w     = t >> 6;
    const int lane  = t & 63;
    const float4* seg4 = reinterpret_cast<const float4*>(
        logits + (size_t)row * VOCABSZ + ebase);
    float* rbv = reinterpret_cast<float*>(&tup[w][0]);   // in-place expansion
    int*   rbi = &rbix[w][0];

    float s0 = 0.f, s1 = 0.f, s2 = 0.f, s3 = 0.f;
    float thr = THRY;
    int   cnt = 0;                   // wave-uniform tuple count
    bool  ovf = false;

#define STEP(I, P) do {                                                        \
        const float y0 = (P).x * LOG2E, y1 = (P).y * LOG2E;                    \
        const float y2 = (P).z * LOG2E, y3 = (P).w * LOG2E;                    \
        s0 += EXP2(y0); s1 += EXP2(y1); s2 += EXP2(y2); s3 += EXP2(y3);        \
        const float mx = fmaxf(fmaxf(y0, y1), fmaxf(y2, y3));                  \
        if (__any(mx > thr)) {                                                 \
            const unsigned long long mk = __ballot(mx > thr);                  \
            const int pos = cnt + __popcll(mk & ((1ull << lane) - 1ull));      \
            if (mx > thr && pos < TCAP) {                                      \
                tup[w][pos] = make_float4(y0, y1, y2, y3);                     \
                tub[w][pos] = ebase + (I) * 1024 + t * 4;                      \
            }                                                                  \
            cnt += __popcll(mk);                                               \
            if (cnt > TGUARD) { ovf = true; thr = FLT_MAX; }                   \
        }                                                                      \
    } while (0)

    // depth-4 prefetch; rolled main loop (15 iters x 4 steps = steps 0..59)
    float4 A0 = seg4[0 * 256 + t];
    float4 A1 = seg4[1 * 256 + t];
    float4 A2 = seg4[2 * 256 + t];
    float4 A3 = seg4[3 * 256 + t];

    const int last = nstep - 1;
    #pragma unroll 1
    for (int g = 0; g < 15; ++g) {
        const int s4 = g * 4 + 4;
        const int i0 = (s4 + 0 < last) ? s4 + 0 : last;
        const int i1 = (s4 + 1 < last) ? s4 + 1 : last;
        const int i2 = (s4 + 2 < last) ? s4 + 2 : last;
        const int i3 = (s4 + 3 < last) ? s4 + 3 : last;
        const float4 N0 = seg4[i0 * 256 + t];
        const float4 N1 = seg4[i1 * 256 + t];
        const float4 N2 = seg4[i2 * 256 + t];
        const float4 N3 = seg4[i3 * 256 + t];

        STEP(g * 4 + 0, A0); STEP(g * 4 + 1, A1);
        STEP(g * 4 + 2, A2); STEP(g * 4 + 3, A3);

        A0 = N0; A1 = N1; A2 = N2; A3 = N3;
    }
    // epilogue: steps 60, 61 (both), 62 (block0 only)
    STEP(60, A0); STEP(61, A1);
    if (nstep == 63) STEP(62, A2);
#undef STEP

    // ---- cold region from here ----

    // exact wave-local flush over rbv/rbi[0..n): lane r gets r-th winner
    float kv = -FLT_MAX; int ki = 0;
    auto do_flush = [&](int n) {
        kv = -FLT_MAX; ki = 0;
        for (int r = 0; r < KTOP; r++) {
            float bv = -FLT_MAX; int bi = INT_MAX; int bp = -1;
            for (int e = lane; e < n; e += 64) {
                const float v  = rbv[e];
                const int   ii = rbi[e];
                if (v > bv || (v == bv && ii < bi)) { bv = v; bi = ii; bp = e; }
            }
            for (int o = 32; o > 0; o >>= 1) {
                const float ov = __shfl_xor(bv, o);
                const int   oi = __shfl_xor(bi, o);
                const int   op = __shfl_xor(bp, o);
                if (ov > bv || (ov == bv && oi < bi)) { bv = ov; bi = oi; bp = op; }
            }
            if (lane == 0 && bp >= 0) rbv[bp] = -FLT_MAX;   // consume
            if (lane == r) { kv = bv; ki = bi; }
            thr = bv;
        }
    };

    // expand tuples in place (tup[e] bytes == rbv[4e..4e+3] bytes; per-lane
    // read-before-write, disjoint across lanes); count elems > static THRY
    const int nt = (cnt < TCAP) ? cnt : TCAP;
    int above = 0;
    for (int e = lane; e < nt; e += 64) {
        const float4 v = tup[w][e];
        const int    b = tub[w][e];
        above += (v.x > THRY) + (v.y > THRY) + (v.z > THRY) + (v.w > THRY);
        rbv[4 * e + 0] = v.x; rbi[4 * e + 0] = b + 0;
        rbv[4 * e + 1] = v.y; rbi[4 * e + 1] = b + 1;
        rbv[4 * e + 2] = v.z; rbi[4 * e + 2] = b + 2;
        rbv[4 * e + 3] = v.w; rbi[4 * e + 3] = b + 3;
    }
    for (int o = 32; o > 0; o >>= 1) above += __shfl_xor(above, o);

    // block reductions: sum + validity count
    float s = (s0 + s1) + (s2 + s3);
    for (int o = 32; o > 0; o >>= 1) s += __shfl_xor(s, o);
    if (lane == 0) { redS[w] = s; redC[w] = ovf ? -(1 << 20) : above; }
    __syncthreads();
    if (t == 0) wsS[gb] = (redS[0] + redS[1]) + (redS[2] + redS[3]);
    const int blockcnt = redC[0] + redC[1] + redC[2] + redC[3];

    int cnt4 = 4 * nt;
    if (blockcnt < KTOP) {
        // cold exact rescue: rescan this wave's subset with self-raising thr
        thr = -FLT_MAX; cnt4 = 0;
        #pragma unroll 1
        for (int i = 0; i < nstep; ++i) {
            const float4 X = seg4[i * 256 + t];
            const float ys[4] = {X.x * LOG2E, X.y * LOG2E, X.z * LOG2E, X.w * LOG2E};
            #pragma unroll
            for (int j = 0; j < 4; ++j) {
                const bool pr = ys[j] > thr;
                const unsigned long long mk = __ballot(pr);
                if (mk) {
                    const int pos = cnt4 + __popcll(mk & ((1ull << lane) - 1ull));
                    if (pr && pos < RCAP) { rbv[pos] = ys[j]; rbi[pos] = ebase + i * 1024 + t * 4 + j; }
                    cnt4 += __popcll(mk);
                    if (cnt4 > RFLUSH) {
                        do_flush(cnt4);
                        if (lane < KTOP) { rbv[lane] = kv; rbi[lane] = ki; }
                        cnt4 = KTOP;
                    }
                }
            }
        }
    }

    do_flush(cnt4);   // final exact wave top-16 (pads -FLT_MAX if cnt4 < 16)

    // layout: row-major 128 slots/row: row*128 + blk*64 + w*16 + r
    if (lane < KTOP) {
        wsV[(size_t)row * 128 + blk * 64 + w * KTOP + lane] = kv;
        wsI[(size_t)row * 128 + blk * 64 + w * KTOP + lane] = ki;
    }
}

// ---------------------------------------------------------------------------
// Kernel 2: one wave per batch. 16 rows x 128 slots = 2048 candidates
// (32 per lane). Merge per-block sums; score sc = ln2*(y - log2(S)) + bs;
// top-16 with jax tie-break (score desc, flat idx rw*V+idx asc); f32 out.
// ---------------------------------------------------------------------------
__global__ __launch_bounds__(64) void k2_select(const float* __restrict__ wsS,
                                                const float* __restrict__ wsV,
                                                const int* __restrict__ wsI,
                                                const float* __restrict__ beam_scores,
                                                const int* __restrict__ dec_ids,
                                                const int* __restrict__ beam_idx_offset,
                                                float* __restrict__ out) {
    const int batch = blockIdx.x;
    const int lane  = threadIdx.x;   // 0..63

    __shared__ float LSs[NBEAMS], BSs[NBEAMS];
    if (lane < NBEAMS) {
        const int row = batch * NBEAMS + lane;
        LSs[lane] = log2f(wsS[row * 2] + wsS[row * 2 + 1]);
        BSs[lane] = beam_scores[row];
    }
    __syncthreads();

    // slot = p*64 + lane in [0,2048); rw = slot>>7; j = slot&127
    float sc[32]; int cb[32];
    #pragma unroll
    for (int p = 0; p < 32; p++) {
        const int slot = p * 64 + lane;
        const int rw   = slot >> 7;
        const int j    = slot & 127;
        const size_t base = (size_t)(batch * NBEAMS + rw) * 128 + j;
        const float v = wsV[base];               // y-domain (-FLT_MAX pads)
        const int idx = wsI[base];
        sc[p] = (v - LSs[rw]) * LN2 + BSs[rw];
        cb[p] = rw * VOCABSZ + idx;
    }

    unsigned int selmask = 0;
    float fs = 0.f; int fc = 0;       // lane r keeps r-th winner
    for (int r = 0; r < KTOP; r++) {
        float bv = -FLT_MAX; int bi = INT_MAX; int bslot = -1;
        #pragma unroll
        for (int p = 0; p < 32; p++) {
            const bool avail = !((selmask >> p) & 1u);
            if (avail && (sc[p] > bv || (sc[p] == bv && cb[p] < bi))) {
                bv = sc[p]; bi = cb[p]; bslot = p;
            }
        }
        int bl = lane;
        for (int o = 32; o > 0; o >>= 1) {
            const float ov  = __shfl_xor(bv, o);
            const int   oi  = __shfl_xor(bi, o);
            const int   obl = __shfl_xor(bl, o);
            const int   obs = __shfl_xor(bslot, o);
            if (ov > bv || (ov == bv && oi < bi)) { bv = ov; bi = oi; bl = obl; bslot = obs; }
        }
        if (lane == bl) selmask |= (1u << bslot);
        if (lane == r) { fs = bv; fc = bi; }
    }

    if (lane < NBEAMS) {
        const int out_row = batch * NBEAMS + lane;
        const int beam  = fc / VOCABSZ;
        const int token = fc - beam * VOCABSZ;
        float* out0 = out;                          // (1024, 9) ids as f32
        float* out1 = out + ROWS * (CURLEN + 1);    // (1024,) scores
        out1[out_row] = fs;
        const int src = beam + beam_idx_offset[out_row];
        #pragma unroll
        for (int j = 0; j < CURLEN; j++)
            out0[out_row * (CURLEN + 1) + j] = (float)dec_ids[src * CURLEN + j];
        out0[out_row * (CURLEN + 1) + CURLEN] = (float)token;
    }
}

extern "C" void kernel_launch(void* const* d_in, const int* in_sizes, int n_in,
                              void* d_out, int out_size, void* d_ws, size_t ws_size,
                              hipStream_t stream) {
    const float* logits = (const float*)d_in[0];
    const int*   dec    = (const int*)d_in[1];
    const float* bscore = (const float*)d_in[2];
    const int*   bio    = (const int*)d_in[3];

    float* ws  = (float*)d_ws;
    float* wsS = ws;                                   // 2048
    float* wsV = ws + ROWS * SPLIT;                    // 1024*128
    int*   wsI = (int*)(ws + ROWS * SPLIT + (size_t)ROWS * 128);

    k1_scan<<<ROWS * SPLIT, 256, 0, stream>>>(logits, wsS, wsV, wsI);
    k2_select<<<NBATCH, 64, 0, stream>>>(wsS, wsV, wsI, bscore, dec, bio,
                                         (float*)d_out);
}

// Round 12
// 149.541 us; speedup vs baseline: 1.0079x; 1.0079x over previous
//
#include <hip/hip_runtime.h>
#include <cfloat>
#include <climits>

#define ROWS    1024
#define VOCABSZ 128000
#define NBEAMS  16
#define NBATCH  64
#define CURLEN  8
#define KTOP    16
#define WPB     8                    // waves per block (512 threads)
#define NFULL   62                   // full float4-steps (512 f4 each)
#define TAILB   31744                // tail float4 base (62*512); 256 f4s
#define TCAP    96                   // tuple slots per wave
#define TGUARD  80                   // stop appending past this (ovf -> rescue)
#define RCAP    (4 * TCAP)           // rescue/expand per-element capacity
#define RFLUSH  320                  // rescue mid-flush threshold
#define LOG2E   1.4426950408889634f
#define LN2     0.6931471805599453f
#define THRY    (3.30f * LOG2E)      // static threshold, y-domain (~62/row)

#if __has_builtin(__builtin_amdgcn_exp2f)
#define EXP2(x) __builtin_amdgcn_exp2f(x)
#else
#define EXP2(x) exp2f(x)
#endif

// ---------------------------------------------------------------------------
// Kernel 1: one block per row, 8 waves (512 threads), grid 1024 (=4 blocks/CU,
// unchanged from R10-best) -> up to 32 waves/CU if VGPR <= 64 (rotation
// prefetch keeps pressure low; no __launch_bounds__ pin -> no spill risk).
// Tiny rolled hot loop: per step 4 mul + 4 exp2 + 4 add + 3 max + 1 cmp +
// wave-uniform branch; passing lanes store one float4 tuple via one ballot.
// All top-k machinery is cold code after the loop (R10 structure).
// Correctness for ANY input: wave ovf or row above-count<16 -> exact rescan.
// ---------------------------------------------------------------------------
__global__ void k1_scan(const float* __restrict__ logits,
                        float* __restrict__ wsS,
                        float* __restrict__ wsV,
                        int* __restrict__ wsI) {
    __shared__ float4 tup[WPB][TCAP];      // 12 KB (aliased by rescue values)
    __shared__ int    tub[WPB][TCAP];      // 3 KB
    __shared__ int    rbix[WPB][RCAP];     // 12 KB rescue indices
    __shared__ float  redS[WPB];
    __shared__ int    redC[WPB];

    const int row  = blockIdx.x;
    const int t    = threadIdx.x;          // 0..511
    const int w    = t >> 6;
    const int lane = t & 63;
    const float4* seg4 = reinterpret_cast<const float4*>(logits + (size_t)row * VOCABSZ);
    float* rbv = reinterpret_cast<float*>(&tup[w][0]);   // in-place expansion
    int*   rbi = &rbix[w][0];

    float s0 = 0.f, s1 = 0.f, s2 = 0.f, s3 = 0.f;
    float thr = THRY;
    int   cnt = 0;                   // wave-uniform tuple count
    bool  ovf = false;

#define STEP(I, P) do {                                                        \
        const float y0 = (P).x * LOG2E, y1 = (P).y * LOG2E;                    \
        const float y2 = (P).z * LOG2E, y3 = (P).w * LOG2E;                    \
        s0 += EXP2(y0); s1 += EXP2(y1); s2 += EXP2(y2); s3 += EXP2(y3);        \
        const float mx = fmaxf(fmaxf(y0, y1), fmaxf(y2, y3));                  \
        if (__any(mx > thr)) {                                                 \
            const unsigned long long mk = __ballot(mx > thr);                  \
            const int pos = cnt + __popcll(mk & ((1ull << lane) - 1ull));      \
            if (mx > thr && pos < TCAP) {                                      \
                tup[w][pos] = make_float4(y0, y1, y2, y3);                     \
                tub[w][pos] = (I) * 2048 + t * 4;                              \
            }                                                                  \
            cnt += __popcll(mk);                                               \
            if (cnt > TGUARD) { ovf = true; thr = FLT_MAX; }                   \
        }                                                                      \
    } while (0)

    // rotation prefetch depth-4 (consume-then-reissue; 4 buffers only)
    float4 A0 = seg4[0 * 512 + t];
    float4 A1 = seg4[1 * 512 + t];
    float4 A2 = seg4[2 * 512 + t];
    float4 A3 = seg4[3 * 512 + t];

    #pragma unroll 1
    for (int g = 0; g < 15; ++g) {
        const int s = g * 4;
        STEP(s + 0, A0); { const int n = (s + 4 < NFULL) ? s + 4 : NFULL - 1; A0 = seg4[n * 512 + t]; }
        STEP(s + 1, A1); { const int n = (s + 5 < NFULL) ? s + 5 : NFULL - 1; A1 = seg4[n * 512 + t]; }
        STEP(s + 2, A2); { const int n = (s + 6 < NFULL) ? s + 6 : NFULL - 1; A2 = seg4[n * 512 + t]; }
        STEP(s + 3, A3); { const int n = (s + 7 < NFULL) ? s + 7 : NFULL - 1; A3 = seg4[n * 512 + t]; }
    }
    STEP(60, A0); STEP(61, A1);
    // tail: 256 float4 (1024 floats) handled by waves 0..3
    if (t < 256) {
        const float4 X = seg4[TAILB + t];
        STEP(62, X);
    }
#undef STEP

    // ---- cold region from here ----

    float kv = -FLT_MAX; int ki = 0;
    auto do_flush = [&](int n) {
        kv = -FLT_MAX; ki = 0;
        for (int r = 0; r < KTOP; r++) {
            float bv = -FLT_MAX; int bi = INT_MAX; int bp = -1;
            for (int e = lane; e < n; e += 64) {
                const float v  = rbv[e];
                const int   ii = rbi[e];
                if (v > bv || (v == bv && ii < bi)) { bv = v; bi = ii; bp = e; }
            }
            for (int o = 32; o > 0; o >>= 1) {
                const float ov = __shfl_xor(bv, o);
                const int   oi = __shfl_xor(bi, o);
                const int   op = __shfl_xor(bp, o);
                if (ov > bv || (ov == bv && oi < bi)) { bv = ov; bi = oi; bp = op; }
            }
            if (lane == 0 && bp >= 0) rbv[bp] = -FLT_MAX;   // consume
            if (lane == r) { kv = bv; ki = bi; }
            thr = bv;
        }
    };

    // expand tuples in place; count elems above static THRY
    const int nt = (cnt < TCAP) ? cnt : TCAP;
    int above = 0;
    for (int e = lane; e < nt; e += 64) {
        const float4 v = tup[w][e];
        const int    b = tub[w][e];
        above += (v.x > THRY) + (v.y > THRY) + (v.z > THRY) + (v.w > THRY);
        rbv[4 * e + 0] = v.x; rbi[4 * e + 0] = b + 0;
        rbv[4 * e + 1] = v.y; rbi[4 * e + 1] = b + 1;
        rbv[4 * e + 2] = v.z; rbi[4 * e + 2] = b + 2;
        rbv[4 * e + 3] = v.w; rbi[4 * e + 3] = b + 3;
    }
    for (int o = 32; o > 0; o >>= 1) above += __shfl_xor(above, o);

    // block reductions: sum + validity count
    float s = (s0 + s1) + (s2 + s3);
    for (int o = 32; o > 0; o >>= 1) s += __shfl_xor(s, o);
    if (lane == 0) { redS[w] = s; redC[w] = ovf ? -(1 << 20) : above; }
    __syncthreads();
    if (t == 0) {
        float S = 0.f;
        #pragma unroll
        for (int i = 0; i < WPB; i++) S += redS[i];
        wsS[row] = S;
    }
    int blockcnt = 0;
    #pragma unroll
    for (int i = 0; i < WPB; i++) blockcnt += redC[i];

    int cnt4 = 4 * nt;
    if (blockcnt < KTOP) {
        // cold exact rescue: rescan this wave's subset with self-raising thr
        thr = -FLT_MAX; cnt4 = 0;
        #pragma unroll 1
        for (int i = 0; i <= NFULL; ++i) {
            if (i == NFULL && t >= 256) break;
            const float4 X = (i < NFULL) ? seg4[i * 512 + t] : seg4[TAILB + t];
            const float ys[4] = {X.x * LOG2E, X.y * LOG2E, X.z * LOG2E, X.w * LOG2E};
            #pragma unroll
            for (int j = 0; j < 4; ++j) {
                const bool pr = ys[j] > thr;
                const unsigned long long mk = __ballot(pr);
                if (mk) {
                    const int pos = cnt4 + __popcll(mk & ((1ull << lane) - 1ull));
                    if (pr && pos < RCAP) { rbv[pos] = ys[j]; rbi[pos] = i * 2048 + t * 4 + j; }
                    cnt4 += __popcll(mk);
                    if (cnt4 > RFLUSH) {
                        do_flush(cnt4);
                        if (lane < KTOP) { rbv[lane] = kv; rbi[lane] = ki; }
                        cnt4 = KTOP;
                    }
                }
            }
        }
    }

    do_flush(cnt4);   // final exact wave top-16 (pads -FLT_MAX if cnt4 < 16)

    // layout: 128 slots/row: row*128 + w*16 + r
    if (lane < KTOP) {
        wsV[(size_t)row * 128 + w * KTOP + lane] = kv;
        wsI[(size_t)row * 128 + w * KTOP + lane] = ki;
    }
}

// ---------------------------------------------------------------------------
// Kernel 2: one wave per batch. 16 rows x 128 slots = 2048 candidates
// (32 per lane). Score sc = ln2*(y - log2(S)) + bs; top-16 with jax
// tie-break (score desc, flat idx rw*V+idx asc); f32 out.
// ---------------------------------------------------------------------------
__global__ __launch_bounds__(64) void k2_select(const float* __restrict__ wsS,
                                                const float* __restrict__ wsV,
                                                const int* __restrict__ wsI,
                                                const float* __restrict__ beam_scores,
                                                const int* __restrict__ dec_ids,
                                                const int* __restrict__ beam_idx_offset,
                                                float* __restrict__ out) {
    const int batch = blockIdx.x;
    const int lane  = threadIdx.x;   // 0..63

    __shared__ float LSs[NBEAMS], BSs[NBEAMS];
    if (lane < NBEAMS) {
        const int row = batch * NBEAMS + lane;
        LSs[lane] = log2f(wsS[row]);
        BSs[lane] = beam_scores[row];
    }
    __syncthreads();

    // slot = p*64 + lane in [0,2048); rw = slot>>7; j = slot&127
    float sc[32]; int cb[32];
    #pragma unroll
    for (int p = 0; p < 32; p++) {
        const int slot = p * 64 + lane;
        const int rw   = slot >> 7;
        const int j    = slot & 127;
        const size_t base = (size_t)(batch * NBEAMS + rw) * 128 + j;
        const float v = wsV[base];               // y-domain (-FLT_MAX pads)
        const int idx = wsI[base];
        sc[p] = (v - LSs[rw]) * LN2 + BSs[rw];
        cb[p] = rw * VOCABSZ + idx;
    }

    unsigned int selmask = 0;
    float fs = 0.f; int fc = 0;       // lane r keeps r-th winner
    for (int r = 0; r < KTOP; r++) {
        float bv = -FLT_MAX; int bi = INT_MAX; int bslot = -1;
        #pragma unroll
        for (int p = 0; p < 32; p++) {
            const bool avail = !((selmask >> p) & 1u);
            if (avail && (sc[p] > bv || (sc[p] == bv && cb[p] < bi))) {
                bv = sc[p]; bi = cb[p]; bslot = p;
            }
        }
        int bl = lane;
        for (int o = 32; o > 0; o >>= 1) {
            const float ov  = __shfl_xor(bv, o);
            const int   oi  = __shfl_xor(bi, o);
            const int   obl = __shfl_xor(bl, o);
            const int   obs = __shfl_xor(bslot, o);
            if (ov > bv || (ov == bv && oi < bi)) { bv = ov; bi = oi; bl = obl; bslot = obs; }
        }
        if (lane == bl) selmask |= (1u << bslot);
        if (lane == r) { fs = bv; fc = bi; }
    }

    if (lane < NBEAMS) {
        const int out_row = batch * NBEAMS + lane;
        const int beam  = fc / VOCABSZ;
        const int token = fc - beam * VOCABSZ;
        float* out0 = out;                          // (1024, 9) ids as f32
        float* out1 = out + ROWS * (CURLEN + 1);    // (1024,) scores
        out1[out_row] = fs;
        const int src = beam + beam_idx_offset[out_row];
        #pragma unroll
        for (int j = 0; j < CURLEN; j++)
            out0[out_row * (CURLEN + 1) + j] = (float)dec_ids[src * CURLEN + j];
        out0[out_row * (CURLEN + 1) + CURLEN] = (float)token;
    }
}

extern "C" void kernel_launch(void* const* d_in, const int* in_sizes, int n_in,
                              void* d_out, int out_size, void* d_ws, size_t ws_size,
                              hipStream_t stream) {
    const float* logits = (const float*)d_in[0];
    const int*   dec    = (const int*)d_in[1];
    const float* bscore = (const float*)d_in[2];
    const int*   bio    = (const int*)d_in[3];

    float* ws  = (float*)d_ws;
    float* wsS = ws;                                   // 1024
    float* wsV = ws + ROWS;                            // 1024*128
    int*   wsI = (int*)(ws + ROWS + (size_t)ROWS * 128);

    k1_scan<<<ROWS, 512, 0, stream>>>(logits, wsS, wsV, wsI);
    k2_select<<<NBATCH, 64, 0, stream>>>(wsS, wsV, wsI, bscore, dec, bio,
                                         (float*)d_out);
}